// Round 8
// baseline (252.308 us; speedup 1.0000x reference)
//
#include <hip/hip_runtime.h>

// R13: store-issue compaction via L3 row-shifted weight variants.
// R12 (~87us) == R5 (~88us) plateau from two different structures, all pipes
// <60% -> shared cost = VMEM instruction issue: 225 VMEM/wave, stores being
// 150 quarter-wave (16-lane, 64B) instructions = 4x the instruction count
// the bytes need (~30us of TA issue chip-wide).
// Fix: C/D rows 4q+i live in quad q, so 4 variants of the L3 A-frag (variant
// s holds W3 in rows 4s..4s+2; same f16 values -> bitwise-identical dots).
// Tile s of a 64-point group uses variant s -> its outputs land in quad s.
// Merge with 3 cndmasks/tile, then ONE full-wave 256B store per row:
// stores 12 -> 3 per group per field (150 -> 36 per wave). Loads unchanged.
// Geometry: 24 tiles/wave = 6 groups x 4; N%64==0 makes every bounds check
// a wave-uniform scalar per group (no per-lane guards, no tail kernel).
// Numerics bitwise R12: a1 quad-broadcast, B-frag quads>=1 cndmask-zeroed,
// pk_relu_pack (cvt_pkrtz + v_pk_max_f16), biases in the MFMA C operand
// (b3 now replicated to all quads; polluted rows are discarded by the
// quad-select merge, selected lanes see the same b3[i] as before).
//
// Frag layouts (16x16x16, CDNA family):
//   A[m][k]: lane m=lane&15, k = 4*(lane>>4) + j   (4 f16, 2 VGPRs)
//   B[k][n]: lane n=lane&15, k = 4*(lane>>4) + j
//   C/D:     lane n=lane&15, row = 4*(lane>>4) + i (4 fp32)

#define MFMA16(a, b, c) __builtin_amdgcn_mfma_f32_16x16x16f16((a), (b), (c), 0, 0, 0)

#define TPG 4                       // tiles per group (64 points)
#define NG 6                        // groups per wave
#define WAVES_PER_BLOCK 4
#define FPB 2                       // fields per block
#define PTS_PER_WAVE (NG * TPG * 16)                     // 384
#define PTS_PER_BLOCK (PTS_PER_WAVE * WAVES_PER_BLOCK)   // 1536

typedef __fp16 pk16x2 __attribute__((ext_vector_type(2)));   // cvt_pkrtz return
typedef _Float16 half4_t __attribute__((ext_vector_type(4)));
typedef float float4_t __attribute__((ext_vector_type(4)));

union H2I { pk16x2 h; int i; };
union Frag { half4_t v; int i[2]; };

__device__ __forceinline__ int pkrtz(float a, float b) {
    H2I u; u.h = __builtin_amdgcn_cvt_pkrtz(a, b); return u.i;
}

// relu on a packed f16 pair: cvt_pkrtz then v_pk_max_f16 with +0 (R11-proven)
__device__ __forceinline__ int pk_relu_pack(float a, float b) {
    H2I u; u.h = __builtin_amdgcn_cvt_pkrtz(a, b);
    const pk16x2 z = {(__fp16)0.f, (__fp16)0.f};
    u.h = __builtin_elementwise_max(u.h, z);
    return u.i;
}

__global__ __launch_bounds__(256, 4) void fields_r13_kernel(
    const float* __restrict__ x,
    const float* __restrict__ W1, const float* __restrict__ b1,
    const float* __restrict__ W2, const float* __restrict__ b2,
    const float* __restrict__ W3, const float* __restrict__ b3,
    float* __restrict__ out, int N)
{
    const int lane = threadIdx.x & 63;
    const int wave = threadIdx.x >> 6;
    const int q    = lane >> 4;        // quad 0..3
    const int n16  = lane & 15;        // point within tile / row m for A

    // ---- XCD-swizzled decode: chunk c = 8a + r runs on XCD r = c%8 ----
    const int bid = blockIdx.x;
    const int r   = bid & 7;
    const int fg  = (bid >> 3) & 7;    // field group: fields 2*fg, 2*fg+1
    const int a   = bid >> 6;
    const int chunk  = a * 8 + r;
    const int chunks = (N + PTS_PER_BLOCK - 1) / PTS_PER_BLOCK;
    if (chunk >= chunks) return;       // pad blocks (grid rounded to *8)

    const int base = chunk * PTS_PER_BLOCK + wave * PTS_PER_WAVE;
    const bool isq0 = (q == 0);
    const bool isq1 = (q == 1);
    const bool isq2 = (q == 2);
    const bool isq3 = (q == 3);

    // ---- 2 fields' weights -> registers, frag-ready ----
    Frag a1w[FPB], a2w[FPB], a3w[FPB][TPG];
    float4_t b1v[FPB], b2v[FPB], b3v[FPB];
#pragma unroll
    for (int f = 0; f < FPB; ++f) {
        const int d = fg * FPB + f;
        const float* w1 = W1 + (d * 16 + n16) * 3;
        a1w[f].v = (half4_t){(_Float16)w1[0], (_Float16)w1[1],
                             (_Float16)w1[2], (_Float16)0.f};
        const float4_t w2 = *(const float4_t*)(W2 + (d * 16 + n16) * 16 + q * 4);
        a2w[f].v = (half4_t){(_Float16)w2.x, (_Float16)w2.y, (_Float16)w2.z,
                             (_Float16)w2.w};
        // L3 variants: variant s holds W3 rows at m = 4s..4s+2 -> outputs of
        // tile s land in quad s of D. Same f16 values -> identical dots.
#pragma unroll
        for (int s = 0; s < TPG; ++s) {
            const int m = n16 - 4 * s;
            if (m >= 0 && m < 3) {
                const float4_t w3 = *(const float4_t*)(W3 + (d * 3 + m) * 16 + q * 4);
                a3w[f][s].v = (half4_t){(_Float16)w3.x, (_Float16)w3.y,
                                        (_Float16)w3.z, (_Float16)w3.w};
            } else {
                a3w[f][s].i[0] = 0; a3w[f][s].i[1] = 0;
            }
        }
        b1v[f] = *(const float4_t*)(b1 + d * 16 + q * 4);
        b2v[f] = *(const float4_t*)(b2 + d * 16 + q * 4);
        // b3 replicated to ALL quads: quad s rows 4s+i get bias b3[i] (the
        // rows where A-variant s is nonzero); polluted rows are discarded.
        b3v[f] = (float4_t){b3[d * 3 + 0], b3[d * 3 + 1], b3[d * 3 + 2], 0.f};
    }

    // ---- UNIFORM base pointers (SGPR); per-lane index in each access ----
    const float* xp0 = x + base;
    const float* xp1 = xp0 + N;
    const float* xp2 = xp1 + N;
    float* ob[FPB][3];
#pragma unroll
    for (int f = 0; f < FPB; ++f) {
        const int d = fg * FPB + f;
#pragma unroll
        for (int i = 0; i < 3; ++i)
            ob[f][i] = out + (size_t)(d * 3 + i) * N + base;
    }

    // ---- 6 groups of 64 points, double-buffered prefetch ----
    float xb[2][3][TPG];   // [buf][row][tile] — all indices compile-time
    if (base + 64 <= N) {  // prologue: load group 0
#pragma unroll
        for (int s = 0; s < TPG; ++s) {
            xb[0][0][s] = xp0[n16 + s * 16];
            xb[0][1][s] = xp1[n16 + s * 16];
            xb[0][2][s] = xp2[n16 + s * 16];
        }
    }

#pragma unroll
    for (int g = 0; g < NG; ++g) {
        const int b = g & 1;                   // compile-time after unroll
        if (base + (g + 1) * 64 <= N) {        // group g fully valid (scalar)
            if (g + 1 < NG && base + (g + 2) * 64 <= N) {   // prefetch g+1
                const int nb = (g + 1) & 1;
#pragma unroll
                for (int s = 0; s < TPG; ++s) {
                    const int off = n16 + ((g + 1) * TPG + s) * 16;
                    xb[nb][0][s] = xp0[off];
                    xb[nb][1][s] = xp1[off];
                    xb[nb][2][s] = xp2[off];
                }
            }
            // pack x -> B-frags once per group (shared by both fields)
            Frag xf[TPG];
#pragma unroll
            for (int s = 0; s < TPG; ++s) {
                const int p01 = pkrtz(xb[b][0][s], xb[b][1][s]);
                const int p2  = pkrtz(xb[b][2][s], 0.f);
                xf[s].i[0] = isq0 ? p01 : 0;
                xf[s].i[1] = isq0 ? p2  : 0;
            }
#pragma unroll
            for (int f = 0; f < FPB; ++f) {
                float mo0 = 0.f, mo1 = 0.f, mo2 = 0.f;
#pragma unroll
                for (int s = 0; s < TPG; ++s) {
                    float4_t acc = MFMA16(a1w[f].v, xf[s].v, b1v[f]);
                    Frag hf;
                    hf.i[0] = pk_relu_pack(acc.x, acc.y);
                    hf.i[1] = pk_relu_pack(acc.z, acc.w);
                    acc = MFMA16(a2w[f].v, hf.v, b2v[f]);
                    hf.i[0] = pk_relu_pack(acc.x, acc.y);
                    hf.i[1] = pk_relu_pack(acc.z, acc.w);
                    acc = MFMA16(a3w[f][s].v, hf.v, b3v[f]);
                    // quad-select merge: lane 16s+n keeps tile s's outputs
                    if (s == 0) { mo0 = acc.x; mo1 = acc.y; mo2 = acc.z; }
                    else {
                        const bool sel = (s == 1) ? isq1 : (s == 2) ? isq2 : isq3;
                        mo0 = sel ? acc.x : mo0;
                        mo1 = sel ? acc.y : mo1;
                        mo2 = sel ? acc.z : mo2;
                    }
                }
                // full-wave 256B stores: lane 16s+n <-> point g*64+16s+n
                const int off = lane + g * 64;
                ob[f][0][off] = mo0;
                ob[f][1][off] = mo1;
                ob[f][2][off] = mo2;
            }
        } else if (base + g * 64 < N) {
            // partial group (never taken when N%64==0): guarded, q0 stores,
            // variant 0 (= classic W3 rows 0..2) -> R12-tail semantics.
#pragma unroll
            for (int s = 0; s < TPG; ++s) {
                const int off = (g * TPG + s) * 16;
                const int pt = base + off + n16;
                float x0 = 0.f, x1v = 0.f, x2v = 0.f;
                if (isq0 && pt < N) {
                    x0  = xp0[n16 + off];
                    x1v = xp1[n16 + off];
                    x2v = xp2[n16 + off];
                }
                Frag xf1;
                xf1.i[0] = pkrtz(x0, x1v);
                xf1.i[1] = pkrtz(x2v, 0.f);
#pragma unroll
                for (int f = 0; f < FPB; ++f) {
                    float4_t acc = MFMA16(a1w[f].v, xf1.v, b1v[f]);
                    Frag hf;
                    hf.i[0] = pk_relu_pack(acc.x, acc.y);
                    hf.i[1] = pk_relu_pack(acc.z, acc.w);
                    acc = MFMA16(a2w[f].v, hf.v, b2v[f]);
                    hf.i[0] = pk_relu_pack(acc.x, acc.y);
                    hf.i[1] = pk_relu_pack(acc.z, acc.w);
                    acc = MFMA16(a3w[f][0].v, hf.v, b3v[f]);
                    if (isq0 && pt < N) {
                        ob[f][0][n16 + off] = acc.x;
                        ob[f][1][n16 + off] = acc.y;
                        ob[f][2][n16 + off] = acc.z;
                    }
                }
            }
        }
    }
}

extern "C" void kernel_launch(void* const* d_in, const int* in_sizes, int n_in,
                              void* d_out, int out_size, void* d_ws, size_t ws_size,
                              hipStream_t stream) {
    const float* x  = (const float*)d_in[0];
    const float* W1 = (const float*)d_in[1];
    const float* b1 = (const float*)d_in[2];
    const float* W2 = (const float*)d_in[3];
    const float* b2 = (const float*)d_in[4];
    const float* W3 = (const float*)d_in[5];
    const float* b3 = (const float*)d_in[6];
    float* out = (float*)d_out;

    const int N = in_sizes[0] / 3;  // x is [1,3,N]
    const int chunks = (N + PTS_PER_BLOCK - 1) / PTS_PER_BLOCK;   // 652
    const int a_max  = (chunks + 7) / 8;                          // 82
    const int grid   = 8 * 8 * a_max;                             // 5248
    fields_r13_kernel<<<grid, 256, 0, stream>>>(x, W1, b1, W2, b2, W3, b3, out, N);
}

// Round 9
// 240.234 us; speedup vs baseline: 1.0503x; 1.0503x over previous
//
#include <hip/hip_runtime.h>

// R14: minimal-register, full-wave-memory rebuild targeting occupancy.
// Evidence: R11 null (VALU 54->42%, dur flat), R13 null (stores 150->36,
// dur flat) -> neither VALU nor VMEM issue binds. R11 measured 28% occupancy
// (2 waves/SIMD) at VGPR_Count=80 -> MFMA accs/weights overflow to AGPRs in
// the unified file; latency exposed. R14 shrinks state to ~75 regs and asks
// for 6 waves/SIMD, while making every load and store full-wave:
//  - FPB=1 (weights+biases ~32 regs), NG=6 groups x 64 pts per wave.
//  - loads: lane l holds point l (3 full-wave loads/group, 2-deep prefetch);
//    tile s's B-frag = (q==s) ? packed : 0  — same proven mechanism as
//    R5-R13 ("B nonzero in one quad, A broadcast"), quad generalized; MFMA
//    zero-terms add exactly -> bitwise identical.
//  - L3: R13's row-shifted variants, plus C-CHAINING: o = b3rep, then
//    o = MFMA(a3v[s], hf[s], o) for s=0..3 — rows not covered by variant s
//    get +0 (exact), so all 64 points' outputs accumulate into one register
//    quad with zero merge cndmasks. Full-wave 256B stores.
//  - 64 | N  -> every bounds check is a wave-uniform per-group scalar;
//    no per-lane guards, no tail path.
// Numerics bitwise R12/R13: a1 quad-broadcast, B-side quad-select zeroing,
// pk_relu_pack (cvt_pkrtz + v_pk_max_f16 builtin, R11-proven), biases ride
// the MFMA C operand (fp32). Weights RNE-cast, activations RTZ.
//
// Frag layouts (16x16x16, CDNA family):
//   A[m][k]: lane m=lane&15, k = 4*(lane>>4) + j   (4 f16, 2 VGPRs)
//   B[k][n]: lane n=lane&15, k = 4*(lane>>4) + j
//   C/D:     lane n=lane&15, row = 4*(lane>>4) + i (4 fp32)

#define MFMA16(a, b, c) __builtin_amdgcn_mfma_f32_16x16x16f16((a), (b), (c), 0, 0, 0)

#define TPG 4                        // tiles per group (64 points)
#define NG 6                         // groups per wave
#define WAVES_PER_BLOCK 4
#define PTS_PER_WAVE (NG * 64)                           // 384
#define PTS_PER_BLOCK (PTS_PER_WAVE * WAVES_PER_BLOCK)   // 1536

typedef __fp16 pk16x2 __attribute__((ext_vector_type(2)));   // cvt_pkrtz return
typedef _Float16 half4_t __attribute__((ext_vector_type(4)));
typedef float float4_t __attribute__((ext_vector_type(4)));

union H2I { pk16x2 h; int i; };
union Frag { half4_t v; int i[2]; };

__device__ __forceinline__ int pkrtz(float a, float b) {
    H2I u; u.h = __builtin_amdgcn_cvt_pkrtz(a, b); return u.i;
}

// relu on a packed f16 pair: cvt_pkrtz then v_pk_max_f16 with +0 (R11-proven)
__device__ __forceinline__ int pk_relu_pack(float a, float b) {
    H2I u; u.h = __builtin_amdgcn_cvt_pkrtz(a, b);
    const pk16x2 z = {(__fp16)0.f, (__fp16)0.f};
    u.h = __builtin_elementwise_max(u.h, z);
    return u.i;
}

__global__ __launch_bounds__(256, 6) void fields_r14_kernel(
    const float* __restrict__ x,
    const float* __restrict__ W1, const float* __restrict__ b1,
    const float* __restrict__ W2, const float* __restrict__ b2,
    const float* __restrict__ W3, const float* __restrict__ b3,
    float* __restrict__ out, int N)
{
    const int lane = threadIdx.x & 63;
    const int wave = threadIdx.x >> 6;
    const int q    = lane >> 4;        // quad 0..3
    const int n16  = lane & 15;        // row m for A-frags

    // ---- XCD-swizzled decode: chunk c = 8a + r runs on XCD r = c%8;
    //      all 16 field-blocks of a chunk sit in one 128-block window. ----
    const int bid = blockIdx.x;
    const int r   = bid & 7;
    const int d   = (bid >> 3) & 15;   // field
    const int a   = bid >> 7;
    const int chunk  = a * 8 + r;
    const int chunks = (N + PTS_PER_BLOCK - 1) / PTS_PER_BLOCK;
    if (chunk >= chunks) return;       // pad blocks (grid rounded to *8)

    const int base = chunk * PTS_PER_BLOCK + wave * PTS_PER_WAVE;
    const bool isq[TPG] = { q == 0, q == 1, q == 2, q == 3 };

    // ---- field d's weights -> registers, frag-ready ----
    Frag a1, a2, a3v[TPG];
    {
        const float* w1 = W1 + (d * 16 + n16) * 3;
        a1.v = (half4_t){(_Float16)w1[0], (_Float16)w1[1],
                         (_Float16)w1[2], (_Float16)0.f};   // quad-broadcast
        const float4_t w2 = *(const float4_t*)(W2 + (d * 16 + n16) * 16 + q * 4);
        a2.v = (half4_t){(_Float16)w2.x, (_Float16)w2.y, (_Float16)w2.z,
                         (_Float16)w2.w};
        // L3 variants: variant s holds W3 rows at m = 4s..4s+2 (R13-proven)
#pragma unroll
        for (int s = 0; s < TPG; ++s) {
            const int m = n16 - 4 * s;
            if (m >= 0 && m < 3) {
                const float4_t w3 = *(const float4_t*)(W3 + (d * 3 + m) * 16 + q * 4);
                a3v[s].v = (half4_t){(_Float16)w3.x, (_Float16)w3.y,
                                     (_Float16)w3.z, (_Float16)w3.w};
            } else {
                a3v[s].i[0] = 0; a3v[s].i[1] = 0;
            }
        }
    }
    const float4_t b1v = *(const float4_t*)(b1 + d * 16 + q * 4);
    const float4_t b2v = *(const float4_t*)(b2 + d * 16 + q * 4);
    // b3 replicated to all quads; rows outside a variant's coverage keep +b3
    // and are never stored (each lane stores only its own quad's rows).
    const float4_t b3r = (float4_t){b3[d * 3 + 0], b3[d * 3 + 1],
                                    b3[d * 3 + 2], 0.f};

    // ---- UNIFORM base pointers (SGPR); per-lane index = lane + 64g ----
    const float* xp0 = x + base;
    const float* xp1 = xp0 + N;
    const float* xp2 = xp1 + N;
    float* op0 = out + (size_t)(d * 3 + 0) * N + base;
    float* op1 = out + (size_t)(d * 3 + 1) * N + base;
    float* op2 = out + (size_t)(d * 3 + 2) * N + base;

    // ---- per-group scalar validity (64 | N -> groups all-or-nothing) ----
    int nvalid = (N - base) / 64;          // may be <=0 for pad waves
    if (nvalid > NG) nvalid = NG;

    // ---- 2-deep full-wave prefetch ----
    float rb[2][3];                        // [buf][row], static indices
    if (0 < nvalid) {
        rb[0][0] = xp0[lane];
        rb[0][1] = xp1[lane];
        rb[0][2] = xp2[lane];
    }
    if (1 < nvalid) {
        rb[1][0] = xp0[lane + 64];
        rb[1][1] = xp1[lane + 64];
        rb[1][2] = xp2[lane + 64];
    }

#pragma unroll
    for (int g = 0; g < NG; ++g) {
        if (g >= nvalid) break;            // wave-uniform scalar branch
        const int b = g & 1;               // compile-time after unroll

        // pack lane's own point ONCE (2 pkrtz), then quad-select per tile
        const int p01 = pkrtz(rb[b][0], rb[b][1]);
        const int p2  = pkrtz(rb[b][2], 0.f);

        // prefetch group g+2 into the freed buffer
        if (g + 2 < nvalid) {
            rb[b][0] = xp0[lane + (g + 2) * 64];
            rb[b][1] = xp1[lane + (g + 2) * 64];
            rb[b][2] = xp2[lane + (g + 2) * 64];
        }

        Frag xf[TPG];
#pragma unroll
        for (int s = 0; s < TPG; ++s) {
            xf[s].i[0] = isq[s] ? p01 : 0;     // B nonzero only in quad s
            xf[s].i[1] = isq[s] ? p2  : 0;     // (k=4s..4s+2 = x0,x1,x2)
        }

        // layer 1: 4 independent MFMAs (a1 broadcast; zero-B quads inert)
        float4_t acc[TPG];
#pragma unroll
        for (int s = 0; s < TPG; ++s) acc[s] = MFMA16(a1.v, xf[s].v, b1v);
        Frag hf[TPG];
#pragma unroll
        for (int s = 0; s < TPG; ++s) {
            hf[s].i[0] = pk_relu_pack(acc[s].x, acc[s].y);
            hf[s].i[1] = pk_relu_pack(acc[s].z, acc[s].w);
        }
        // layer 2
#pragma unroll
        for (int s = 0; s < TPG; ++s) acc[s] = MFMA16(a2.v, hf[s].v, b2v);
#pragma unroll
        for (int s = 0; s < TPG; ++s) {
            hf[s].i[0] = pk_relu_pack(acc[s].x, acc[s].y);
            hf[s].i[1] = pk_relu_pack(acc[s].z, acc[s].w);
        }
        // layer 3: C-chained variants — tile s's rows land in quad s;
        // untouched rows receive +0 (exact) and carry through.
        float4_t o = b3r;
#pragma unroll
        for (int s = 0; s < TPG; ++s) o = MFMA16(a3v[s].v, hf[s].v, o);

        // full-wave 256B stores: lane l <-> point g*64 + l
        op0[lane + g * 64] = o.x;
        op1[lane + g * 64] = o.y;
        op2[lane + g * 64] = o.z;
    }
}

extern "C" void kernel_launch(void* const* d_in, const int* in_sizes, int n_in,
                              void* d_out, int out_size, void* d_ws, size_t ws_size,
                              hipStream_t stream) {
    const float* x  = (const float*)d_in[0];
    const float* W1 = (const float*)d_in[1];
    const float* b1 = (const float*)d_in[2];
    const float* W2 = (const float*)d_in[3];
    const float* b2 = (const float*)d_in[4];
    const float* W3 = (const float*)d_in[5];
    const float* b3 = (const float*)d_in[6];
    float* out = (float*)d_out;

    const int N = in_sizes[0] / 3;  // x is [1,3,N]
    const int chunks = (N + PTS_PER_BLOCK - 1) / PTS_PER_BLOCK;   // 652
    const int a_max  = (chunks + 7) / 8;                          // 82
    const int grid   = 8 * 16 * a_max;                            // 10496
    fields_r14_kernel<<<grid, 256, 0, stream>>>(x, W1, b1, W2, b2, W3, b3, out, N);
}

// Round 10
// 232.143 us; speedup vs baseline: 1.0869x; 1.0349x over previous
//
#include <hip/hip_runtime.h>

// R15: branch-free straight-line fast path + 2x points per block.
// R14 (~80us kernel) is 2.3x the ~34us memory floor with all pipes <60%.
// Remaining serializer: the per-group `if (g >= nvalid) break` scalar branch
// between groups blocks cross-group compiler scheduling — each group's
// L1->relu->L2->relu->4-deep-C-chained-L3 chain (~300cy) is latency-exposed
// once per group. R15:
//  - fast path (base + PTS_PER_WAVE <= N, all but 3 waves chip-wide):
//    straight-line, ZERO control flow between groups -> compiler pipelines
//    group g+1's loads/pack/L1 into group g's chain shadows.
//  - NG 6 -> 12 (PTS_PER_BLOCK 3072): halves block count & per-point setup.
//  - tail waves: R14's exact guarded loop (group-granular, 64 | N).
// Numerics bitwise R14: a1 quad-broadcast, B quad-select zeroing, R13's L3
// row-shifted variants C-chained (untouched rows +0 exact), pk_relu_pack
// (cvt_pkrtz + v_pk_max_f16), biases in MFMA C operand, full-wave 256B
// loads/stores, 2-deep prefetch, launch_bounds(256,6), XCD swizzle.
//
// Frag layouts (16x16x16, CDNA family):
//   A[m][k]: lane m=lane&15, k = 4*(lane>>4) + j   (4 f16, 2 VGPRs)
//   B[k][n]: lane n=lane&15, k = 4*(lane>>4) + j
//   C/D:     lane n=lane&15, row = 4*(lane>>4) + i (4 fp32)

#define MFMA16(a, b, c) __builtin_amdgcn_mfma_f32_16x16x16f16((a), (b), (c), 0, 0, 0)

#define TPG 4                        // tiles per group (64 points)
#define NG 12                        // groups per wave
#define WAVES_PER_BLOCK 4
#define PTS_PER_WAVE (NG * 64)                           // 768
#define PTS_PER_BLOCK (PTS_PER_WAVE * WAVES_PER_BLOCK)   // 3072

typedef __fp16 pk16x2 __attribute__((ext_vector_type(2)));   // cvt_pkrtz return
typedef _Float16 half4_t __attribute__((ext_vector_type(4)));
typedef float float4_t __attribute__((ext_vector_type(4)));

union H2I { pk16x2 h; int i; };
union Frag { half4_t v; int i[2]; };

__device__ __forceinline__ int pkrtz(float a, float b) {
    H2I u; u.h = __builtin_amdgcn_cvt_pkrtz(a, b); return u.i;
}

// relu on a packed f16 pair: cvt_pkrtz then v_pk_max_f16 with +0 (R11-proven)
__device__ __forceinline__ int pk_relu_pack(float a, float b) {
    H2I u; u.h = __builtin_amdgcn_cvt_pkrtz(a, b);
    const pk16x2 z = {(__fp16)0.f, (__fp16)0.f};
    u.h = __builtin_elementwise_max(u.h, z);
    return u.i;
}

__global__ __launch_bounds__(256, 6) void fields_r15_kernel(
    const float* __restrict__ x,
    const float* __restrict__ W1, const float* __restrict__ b1,
    const float* __restrict__ W2, const float* __restrict__ b2,
    const float* __restrict__ W3, const float* __restrict__ b3,
    float* __restrict__ out, int N)
{
    const int lane = threadIdx.x & 63;
    const int wave = threadIdx.x >> 6;
    const int q    = lane >> 4;        // quad 0..3
    const int n16  = lane & 15;        // row m for A-frags

    // ---- XCD-swizzled decode: chunk c = 8a + r runs on XCD r = c%8;
    //      all 16 field-blocks of a chunk sit in one 128-block window. ----
    const int bid = blockIdx.x;
    const int r   = bid & 7;
    const int d   = (bid >> 3) & 15;   // field
    const int a   = bid >> 7;
    const int chunk  = a * 8 + r;
    const int chunks = (N + PTS_PER_BLOCK - 1) / PTS_PER_BLOCK;
    if (chunk >= chunks) return;       // pad blocks (grid rounded to *8)

    const int base = chunk * PTS_PER_BLOCK + wave * PTS_PER_WAVE;
    const bool isq[TPG] = { q == 0, q == 1, q == 2, q == 3 };

    // ---- field d's weights -> registers, frag-ready (R14-exact) ----
    Frag a1, a2, a3v[TPG];
    {
        const float* w1 = W1 + (d * 16 + n16) * 3;
        a1.v = (half4_t){(_Float16)w1[0], (_Float16)w1[1],
                         (_Float16)w1[2], (_Float16)0.f};   // quad-broadcast
        const float4_t w2 = *(const float4_t*)(W2 + (d * 16 + n16) * 16 + q * 4);
        a2.v = (half4_t){(_Float16)w2.x, (_Float16)w2.y, (_Float16)w2.z,
                         (_Float16)w2.w};
#pragma unroll
        for (int s = 0; s < TPG; ++s) {
            const int m = n16 - 4 * s;
            if (m >= 0 && m < 3) {
                const float4_t w3 = *(const float4_t*)(W3 + (d * 3 + m) * 16 + q * 4);
                a3v[s].v = (half4_t){(_Float16)w3.x, (_Float16)w3.y,
                                     (_Float16)w3.z, (_Float16)w3.w};
            } else {
                a3v[s].i[0] = 0; a3v[s].i[1] = 0;
            }
        }
    }
    const float4_t b1v = *(const float4_t*)(b1 + d * 16 + q * 4);
    const float4_t b2v = *(const float4_t*)(b2 + d * 16 + q * 4);
    const float4_t b3r = (float4_t){b3[d * 3 + 0], b3[d * 3 + 1],
                                    b3[d * 3 + 2], 0.f};

    // ---- UNIFORM base pointers (SGPR); per-lane index = lane + 64g ----
    const float* xp0 = x + base;
    const float* xp1 = xp0 + N;
    const float* xp2 = xp1 + N;
    float* op0 = out + (size_t)(d * 3 + 0) * N + base;
    float* op1 = out + (size_t)(d * 3 + 1) * N + base;
    float* op2 = out + (size_t)(d * 3 + 2) * N + base;

    if (base + PTS_PER_WAVE <= N) {
        // ===== fast path: straight-line, no control flow between groups ====
        float rb[2][3];                    // 2-deep prefetch, static indices
        rb[0][0] = xp0[lane];      rb[0][1] = xp1[lane];      rb[0][2] = xp2[lane];
        rb[1][0] = xp0[lane + 64]; rb[1][1] = xp1[lane + 64]; rb[1][2] = xp2[lane + 64];

#pragma unroll
        for (int g = 0; g < NG; ++g) {
            const int b = g & 1;           // compile-time after unroll

            // pack lane's own point ONCE, then quad-select per tile
            const int p01 = pkrtz(rb[b][0], rb[b][1]);
            const int p2  = pkrtz(rb[b][2], 0.f);

            if (g + 2 < NG) {              // prefetch group g+2 (unrolled-const)
                rb[b][0] = xp0[lane + (g + 2) * 64];
                rb[b][1] = xp1[lane + (g + 2) * 64];
                rb[b][2] = xp2[lane + (g + 2) * 64];
            }

            Frag xf[TPG];
#pragma unroll
            for (int s = 0; s < TPG; ++s) {
                xf[s].i[0] = isq[s] ? p01 : 0;   // B nonzero only in quad s
                xf[s].i[1] = isq[s] ? p2  : 0;
            }

            float4_t acc[TPG];
#pragma unroll
            for (int s = 0; s < TPG; ++s) acc[s] = MFMA16(a1.v, xf[s].v, b1v);
            Frag hf[TPG];
#pragma unroll
            for (int s = 0; s < TPG; ++s) {
                hf[s].i[0] = pk_relu_pack(acc[s].x, acc[s].y);
                hf[s].i[1] = pk_relu_pack(acc[s].z, acc[s].w);
            }
#pragma unroll
            for (int s = 0; s < TPG; ++s) acc[s] = MFMA16(a2.v, hf[s].v, b2v);
#pragma unroll
            for (int s = 0; s < TPG; ++s) {
                hf[s].i[0] = pk_relu_pack(acc[s].x, acc[s].y);
                hf[s].i[1] = pk_relu_pack(acc[s].z, acc[s].w);
            }
            float4_t o = b3r;              // C-chained L3 variants (exact)
#pragma unroll
            for (int s = 0; s < TPG; ++s) o = MFMA16(a3v[s].v, hf[s].v, o);

            op0[lane + g * 64] = o.x;      // full-wave 256B stores
            op1[lane + g * 64] = o.y;
            op2[lane + g * 64] = o.z;
        }
    } else {
        // ===== tail path (3 waves chip-wide): R14's guarded group loop ====
        int nvalid = (N > base) ? (N - base) / 64 : 0;   // 64 | N
        if (nvalid > NG) nvalid = NG;

        float rb[2][3];
        if (0 < nvalid) {
            rb[0][0] = xp0[lane]; rb[0][1] = xp1[lane]; rb[0][2] = xp2[lane];
        }
        if (1 < nvalid) {
            rb[1][0] = xp0[lane + 64]; rb[1][1] = xp1[lane + 64]; rb[1][2] = xp2[lane + 64];
        }

#pragma unroll
        for (int g = 0; g < NG; ++g) {
            if (g >= nvalid) break;        // wave-uniform scalar branch
            const int b = g & 1;

            const int p01 = pkrtz(rb[b][0], rb[b][1]);
            const int p2  = pkrtz(rb[b][2], 0.f);

            if (g + 2 < nvalid) {
                rb[b][0] = xp0[lane + (g + 2) * 64];
                rb[b][1] = xp1[lane + (g + 2) * 64];
                rb[b][2] = xp2[lane + (g + 2) * 64];
            }

            Frag xf[TPG];
#pragma unroll
            for (int s = 0; s < TPG; ++s) {
                xf[s].i[0] = isq[s] ? p01 : 0;
                xf[s].i[1] = isq[s] ? p2  : 0;
            }

            float4_t acc[TPG];
#pragma unroll
            for (int s = 0; s < TPG; ++s) acc[s] = MFMA16(a1.v, xf[s].v, b1v);
            Frag hf[TPG];
#pragma unroll
            for (int s = 0; s < TPG; ++s) {
                hf[s].i[0] = pk_relu_pack(acc[s].x, acc[s].y);
                hf[s].i[1] = pk_relu_pack(acc[s].z, acc[s].w);
            }
#pragma unroll
            for (int s = 0; s < TPG; ++s) acc[s] = MFMA16(a2.v, hf[s].v, b2v);
#pragma unroll
            for (int s = 0; s < TPG; ++s) {
                hf[s].i[0] = pk_relu_pack(acc[s].x, acc[s].y);
                hf[s].i[1] = pk_relu_pack(acc[s].z, acc[s].w);
            }
            float4_t o = b3r;
#pragma unroll
            for (int s = 0; s < TPG; ++s) o = MFMA16(a3v[s].v, hf[s].v, o);

            op0[lane + g * 64] = o.x;
            op1[lane + g * 64] = o.y;
            op2[lane + g * 64] = o.z;
        }
    }
}

extern "C" void kernel_launch(void* const* d_in, const int* in_sizes, int n_in,
                              void* d_out, int out_size, void* d_ws, size_t ws_size,
                              hipStream_t stream) {
    const float* x  = (const float*)d_in[0];
    const float* W1 = (const float*)d_in[1];
    const float* b1 = (const float*)d_in[2];
    const float* W2 = (const float*)d_in[3];
    const float* b2 = (const float*)d_in[4];
    const float* W3 = (const float*)d_in[5];
    const float* b3 = (const float*)d_in[6];
    float* out = (float*)d_out;

    const int N = in_sizes[0] / 3;  // x is [1,3,N]
    const int chunks = (N + PTS_PER_BLOCK - 1) / PTS_PER_BLOCK;   // 326
    const int a_max  = (chunks + 7) / 8;                          // 41
    const int grid   = 8 * 16 * a_max;                            // 5248
    fields_r15_kernel<<<grid, 256, 0, stream>>>(x, W1, b1, W2, b2, W3, b3, out, N);
}